// Round 16
// baseline (542.768 us; speedup 1.0000x reference)
//
#include <hip/hip_runtime.h>
#include <cstddef>
#include <cstdint>

typedef unsigned short u16;
typedef unsigned int   u32;
typedef __bf16  bf16x8 __attribute__((ext_vector_type(8)));
typedef float   f32x4  __attribute__((ext_vector_type(4)));

#define DEV __device__ __forceinline__

DEV float b2f(u16 u) { union { u32 i; float f; } c; c.i = ((u32)u) << 16; return c.f; }
DEV u16 f2b(float x) { union { float f; u32 i; } c; c.f = x; u32 b = c.i;
                       return (u16)((b + 0x7FFFu + ((b >> 16) & 1u)) >> 16); }
DEV float sigm(float x)  { return 1.0f / (1.0f + __expf(-x)); }
DEV float tanh_(float x) { return 1.0f - 2.0f / (1.0f + __expf(2.0f * x)); }
DEV float gelu_(float x) { return 0.5f * x * (1.0f + erff(x * 0.70710678118654752f)); }

DEV void u4tof8(uint4 v, float* f) {
    f[0] = b2f((u16)(v.x & 0xFFFF)); f[1] = b2f((u16)(v.x >> 16));
    f[2] = b2f((u16)(v.y & 0xFFFF)); f[3] = b2f((u16)(v.y >> 16));
    f[4] = b2f((u16)(v.z & 0xFFFF)); f[5] = b2f((u16)(v.z >> 16));
    f[6] = b2f((u16)(v.w & 0xFFFF)); f[7] = b2f((u16)(v.w >> 16));
}
DEV uint4 f8tou4(const float* f) {
    uint4 v;
    v.x = (u32)f2b(f[0]) | ((u32)f2b(f[1]) << 16);
    v.y = (u32)f2b(f[2]) | ((u32)f2b(f[3]) << 16);
    v.z = (u32)f2b(f[4]) | ((u32)f2b(f[5]) << 16);
    v.w = (u32)f2b(f[6]) | ((u32)f2b(f[7]) << 16);
    return v;
}

// ---- workspace byte offsets; total 144,015,360 B (<=144,113,664 proven) ----
#define OB_PRU   0ull            // PrU [40000][256] bf16 (x@Wr^T + urb)
#define OB_PZX   20480000ull     // Pzx [40000][256] bf16 (x@Wzx^T, depth-invariant)
#define OB_PHX   40960000ull     // Phx [40000][256] bf16
#define OB_H     61440000ull     // h   [40000][256] bf16
#define OB_UH    81920000ull     // Uh [40000][256] bf16; nei overlay; Br/Box overlay in prologue
#define OB_SH    102400000ull    // sumh [40000][256] bf16 ; x overlays in prologue
#define OB_SGH   122880000ull    // sumgh [40000][256] bf16 ; fb overlays in prologue
#define OB_BZX   143360000ull    // [256][128] Wz[:, :111] K-pad
#define OB_BZH   143425536ull    // [256][256] Wz[:, 111:]
#define OB_BHX   143556608ull    // [256][128] Wh[:, :111]
#define OB_BHH   143622144ull    // [256][256] Wh[:, 111:]
#define OB_BU    143753216ull    // [256][256] U_r
#define OB_BOH   143884288ull    // [256][256] Wo[:, 98:]
#define OB_BR    OB_UH           // [256][128] Wr (prologue only; clobbered by Uh)
#define OB_BOX   (OB_UH + 65536ull) // [256][128] Wo[:, :98] (prologue only)
#define WS_BYTES 144015360ull

// REGISTER LAW (R3-R15): MFMA kernels spill catastrophically above ~92 live
// VGPRs; all GEMMs single-accumulator acc[4][2].
// Z-TILE LAW (R15): same-thread phase hand-off via LDS BEAT registers
// (z-in-regs 57us vs z-in-LDS 45.5us). Keep Zs in LDS.
// OCCUPANCY LAW (R13/R14): K<=256 GEMMs are latency-bound; smaller LDS /
// more blocks-per-CU wins when no spill results.

// XCD-aware bijective swizzle (T1/m204).
DEV int xcd_swz(int bid, int nwg) {
    int q = nwg >> 3, r = nwg & 7;
    int xcd = bid & 7, idx = bid >> 3;
    return (xcd < r ? xcd * (q + 1) : r * (q + 1) + (xcd - r) * q) + idx;
}

// ---------------------------------------------------------------------------
// Weight repack -> [N][K] bf16. Grid 256x256.
__global__ __launch_bounds__(256) void k_repack(
    const float* __restrict__ Wz, const float* __restrict__ Wr,
    const float* __restrict__ Ur, const float* __restrict__ Wh,
    const float* __restrict__ Wo,
    u16* __restrict__ BzxT, u16* __restrict__ BzhT, u16* __restrict__ BhxT,
    u16* __restrict__ BhhT, u16* __restrict__ BuT, u16* __restrict__ BohT,
    u16* __restrict__ BrT, u16* __restrict__ BoxT) {
    int idx = blockIdx.x * 256 + threadIdx.x;   // 0..65535
    {
        int n = idx >> 8, k = idx & 255;
        BzhT[idx] = f2b(Wz[n * 367 + 111 + k]);
        BhhT[idx] = f2b(Wh[n * 367 + 111 + k]);
        BuT[idx]  = f2b(Ur[idx]);
        BohT[idx] = f2b(Wo[n * 354 + 98 + k]);
    }
    if (idx < 32768) {
        int n = idx >> 7, k = idx & 127;
        BzxT[idx] = f2b(k < 111 ? Wz[n * 367 + k] : 0.0f);
        BhxT[idx] = f2b(k < 111 ? Wh[n * 367 + k] : 0.0f);
        BrT[idx]  = f2b(k < 111 ? Wr[n * 111 + k] : 0.0f);
        BoxT[idx] = f2b(k < 98  ? Wo[n * 354 + k] : 0.0f);
    }
}

// x[e][c] (bf16, [40000][128], zero pad). Grid 20000x256.
__global__ __launch_bounds__(256) void k_build_x(const float* __restrict__ fnode,
                                                 const float* __restrict__ fmess,
                                                 u16* __restrict__ x) {
    int e = (blockIdx.x << 1) + (threadIdx.x >> 7);
    int c = threadIdx.x & 127;
    int src = (int)fmess[(size_t)e * 15];
    float v = 0.0f;
    if (c < 98)       v = fnode[(size_t)src * 98 + c];
    else if (c < 111) v = fmess[(size_t)e * 15 + 2 + (c - 98)];
    x[(size_t)e * 128 + c] = f2b(v);
}

// fb [20000][128] bf16 zero-padded. Grid 10000x256.
__global__ __launch_bounds__(256) void k_build_fb(const float* __restrict__ fnode,
                                                  u16* __restrict__ fb) {
    int idx = blockIdx.x * 256 + threadIdx.x;
    int n = idx >> 7, c = idx & 127;
    fb[idx] = f2b(c < 98 ? fnode[(size_t)n * 98 + c] : 0.0f);
}

// ---------------------------------------------------------------------------
// R11 template: BM=128, BN=64, BK=64. 256 threads = 4 waves (2M x 2N),
// wave tile 64x32, acc[4][2]. Swizzle byte ^= (row&7)<<4.
DEV void ldA(const u16* __restrict__ g, size_t row0, int ld, int k0, int tid, uint4* v) {
    #pragma unroll
    for (int it = 0; it < 4; ++it) {
        int r = it * 32 + (tid >> 3);
        int c = (tid & 7) << 3;
        v[it] = *(const uint4*)(g + (row0 + (size_t)r) * ld + k0 + c);
    }
}
DEV void ldB(const u16* __restrict__ g, size_t row0, int ld, int k0, int tid, uint4* v) {
    #pragma unroll
    for (int it = 0; it < 2; ++it) {
        int r = it * 32 + (tid >> 3);
        int c = (tid & 7) << 3;
        v[it] = *(const uint4*)(g + (row0 + (size_t)r) * ld + k0 + c);
    }
}
DEV void wrA(u16* s, int tid, const uint4* v) {
    #pragma unroll
    for (int it = 0; it < 4; ++it) {
        int r = it * 32 + (tid >> 3);
        int c = (tid & 7) << 3;
        int byte = (((r << 6) + c) << 1) ^ ((r & 7) << 4);
        *(uint4*)((char*)s + byte) = v[it];
    }
}
DEV void wrB(u16* s, int tid, const uint4* v) {
    #pragma unroll
    for (int it = 0; it < 2; ++it) {
        int r = it * 32 + (tid >> 3);
        int c = (tid & 7) << 3;
        int byte = (((r << 6) + c) << 1) ^ ((r & 7) << 4);
        *(uint4*)((char*)s + byte) = v[it];
    }
}
// Swapped-operand MFMA: acc[i][j][q] = C[row_l+16i][col_l+16j+q]
DEV void mma_step(const u16* As, const u16* Bs, f32x4 acc[4][2], int lane, int wr, int wc) {
    int rb = (wr << 6) + (lane & 15);
    int cb = (wc << 5) + (lane & 15);
    int ko = (lane >> 4) << 3;
    #pragma unroll
    for (int kh = 0; kh < 2; ++kh) {
        bf16x8 a[4], b[2];
        #pragma unroll
        for (int i = 0; i < 4; ++i) {
            int ar = rb + (i << 4);
            a[i] = *(const bf16x8*)((const char*)As +
                   ((((ar << 6) + (kh << 5) + ko) << 1) ^ ((ar & 7) << 4)));
        }
        #pragma unroll
        for (int j = 0; j < 2; ++j) {
            int br = cb + (j << 4);
            b[j] = *(const bf16x8*)((const char*)Bs +
                   ((((br << 6) + (kh << 5) + ko) << 1) ^ ((br & 7) << 4)));
        }
        #pragma unroll
        for (int i = 0; i < 4; ++i)
            #pragma unroll
            for (int j = 0; j < 2; ++j)
                acc[i][j] = __builtin_amdgcn_mfma_f32_16x16x32_bf16(b[j], a[i], acc[i][j], 0, 0, 0);
    }
}

#define GT_PROLOG(BIDX, NWG)                                   \
    int tid = threadIdx.x, lane = tid & 63, w = tid >> 6;      \
    int wr = w >> 1, wc = w & 1;                               \
    int bid = xcd_swz((BIDX), (NWG));                          \
    int bm = bid >> 2, bn = bid & 3;                           \
    size_t m0 = (size_t)bm << 7; size_t n0 = (size_t)(bn << 6);\
    int row_l = (wr << 6) + (lane & 15);                       \
    int col_l = (wc << 5) + ((lane >> 4) << 2);

#define ACC_INIT(A)                                            \
    { f32x4 zz = {0.f, 0.f, 0.f, 0.f};                         \
      _Pragma("unroll") for (int i = 0; i < 4; ++i)            \
      _Pragma("unroll") for (int j = 0; j < 2; ++j) A[i][j] = zz; }

#define DB_STEP(CUR_A, CUR_B, NXT_A, NXT_B, LD_NEXT2)          \
    mma_step(CUR_A, CUR_B, acc, lane, wr, wc);                 \
    wrA(NXT_A, tid, ra); wrB(NXT_B, tid, rb);                  \
    __syncthreads();                                           \
    LD_NEXT2;

// Single-buffer step (for 40KB k_mg_zh): write staged regs, barrier, issue
// next loads, mma, barrier (protects next overwrite).
#define SB_STEP(LD_NEXT2)                                      \
    wrA(As, tid, ra); wrB(Bs, tid, rb);                        \
    __syncthreads();                                           \
    LD_NEXT2;                                                  \
    mma_step(As, Bs, acc, lane, wr, wc);                       \
    __syncthreads();

// ---------------------------------------------------------------------------
// Merged prologue GEMMs (K=128): sub 0: PrU = x@BrT^T + urb; sub 1: Pzx;
// sub 2: Phx. Grid 3756 (3 x 1252).
__global__ __launch_bounds__(256) void k_mg_pre(
    const u16* __restrict__ x, const u16* __restrict__ BrT,
    const u16* __restrict__ BzxT, const u16* __restrict__ BhxT,
    const float* __restrict__ urb,
    u16* __restrict__ PrU, u16* __restrict__ Pzx, u16* __restrict__ Phx) {
    __shared__ u16 As0[8192], As1[8192], Bs0[4096], Bs1[4096];
    int sub = blockIdx.x / 1252;
    int inner = blockIdx.x - sub * 1252;
    const u16* BT = sub == 0 ? BrT : (sub == 1 ? BzxT : BhxT);
    const float* bias = sub == 0 ? urb : (const float*)0;
    u16* out = sub == 0 ? PrU : (sub == 1 ? Pzx : Phx);
    GT_PROLOG(inner, 1252)
    f32x4 acc[4][2]; ACC_INIT(acc)
    uint4 ra[4], rb[2];
    ldA(x, m0, 128, 0, tid, ra); ldB(BT, n0, 128, 0, tid, rb);
    wrA(As0, tid, ra); wrB(Bs0, tid, rb);
    __syncthreads();
    ldA(x, m0, 128, 64, tid, ra); ldB(BT, n0, 128, 64, tid, rb);
    DB_STEP(As0, Bs0, As1, Bs1, ;)
    mma_step(As1, Bs1, acc, lane, wr, wc);
    #pragma unroll
    for (int mi = 0; mi < 4; ++mi) {
        int m = (int)m0 + row_l + (mi << 4);
        if (m >= 40000) continue;
        #pragma unroll
        for (int ni = 0; ni < 2; ++ni) {
            int col = (int)n0 + col_l + (ni << 4);
            float4 ub = bias ? *(const float4*)(bias + col)
                             : make_float4(0.f, 0.f, 0.f, 0.f);
            ushort4 o;
            o.x = f2b(acc[mi][ni][0] + ub.x); o.y = f2b(acc[mi][ni][1] + ub.y);
            o.z = f2b(acc[mi][ni][2] + ub.z); o.w = f2b(acc[mi][ni][3] + ub.w);
            *(ushort4*)(out + (size_t)m * 256 + col) = o;
        }
    }
}

// Pn = fb @ BoxT^T -> f32 d_out. K=128, M=20000. Grid 628.
__global__ __launch_bounds__(256) void k_mg_pn(
    const u16* __restrict__ fb, const u16* __restrict__ BT,
    float* __restrict__ out) {
    __shared__ u16 As0[8192], As1[8192], Bs0[4096], Bs1[4096];
    GT_PROLOG((int)blockIdx.x, (int)gridDim.x)
    f32x4 acc[4][2]; ACC_INIT(acc)
    uint4 ra[4], rb[2];
    ldA(fb, m0, 128, 0, tid, ra); ldB(BT, n0, 128, 0, tid, rb);
    wrA(As0, tid, ra); wrB(Bs0, tid, rb);
    __syncthreads();
    ldA(fb, m0, 128, 64, tid, ra); ldB(BT, n0, 128, 64, tid, rb);
    DB_STEP(As0, Bs0, As1, Bs1, ;)
    mma_step(As1, Bs1, acc, lane, wr, wc);
    #pragma unroll
    for (int mi = 0; mi < 4; ++mi) {
        int m = (int)m0 + row_l + (mi << 4);
        if (m >= 20000) continue;
        #pragma unroll
        for (int ni = 0; ni < 2; ++ni) {
            int col = (int)n0 + col_l + (ni << 4);
            #pragma unroll
            for (int q = 0; q < 4; ++q)
                out[(size_t)m * 256 + col + q] = acc[mi][ni][q];
        }
    }
}

// Depth-1 elementwise: h = sigm(Pzx+bz)*tanh(Phx+bh), row0 mask. Grid 5000.
__global__ __launch_bounds__(256) void k_d1(
    const u16* __restrict__ Pzx, const u16* __restrict__ Phx,
    const float* __restrict__ bz, const float* __restrict__ bh,
    u16* __restrict__ h) {
    int idx = blockIdx.x * 256 + threadIdx.x;
    int e = idx >> 5, c = (idx & 31) << 3;
    size_t o = (size_t)e * 256 + c;
    float pz[8], ph[8], r[8];
    u4tof8(*(const uint4*)(Pzx + o), pz);
    u4tof8(*(const uint4*)(Phx + o), ph);
    #pragma unroll
    for (int q = 0; q < 8; ++q)
        r[q] = (e == 0) ? 0.0f : sigm(pz[q] + bz[c + q]) * tanh_(ph[q] + bh[c + q]);
    *(uint4*)(h + o) = f8tou4(r);
}

// Uh = h @ BuT^T. K=256, 4 dbuf steps. Grid 1252.
__global__ __launch_bounds__(256) void k_mg_uh(
    const u16* __restrict__ A, const u16* __restrict__ BT, u16* __restrict__ C) {
    __shared__ u16 As0[8192], As1[8192], Bs0[4096], Bs1[4096];
    GT_PROLOG((int)blockIdx.x, (int)gridDim.x)
    f32x4 acc[4][2]; ACC_INIT(acc)
    uint4 ra[4], rb[2];
    ldA(A, m0, 256, 0, tid, ra); ldB(BT, n0, 256, 0, tid, rb);
    wrA(As0, tid, ra); wrB(Bs0, tid, rb);
    __syncthreads();
    ldA(A, m0, 256, 64, tid, ra); ldB(BT, n0, 256, 64, tid, rb);
    DB_STEP(As0, Bs0, As1, Bs1, (ldA(A, m0, 256, 128, tid, ra), ldB(BT, n0, 256, 128, tid, rb)))
    DB_STEP(As1, Bs1, As0, Bs0, (ldA(A, m0, 256, 192, tid, ra), ldB(BT, n0, 256, 192, tid, rb)))
    DB_STEP(As0, Bs0, As1, Bs1, ;)
    mma_step(As1, Bs1, acc, lane, wr, wc);
    #pragma unroll
    for (int mi = 0; mi < 4; ++mi) {
        int m = (int)m0 + row_l + (mi << 4);
        if (m >= 40000) continue;
        #pragma unroll
        for (int ni = 0; ni < 2; ++ni) {
            int col = (int)n0 + col_l + (ni << 4);
            ushort4 o;
            o.x = f2b(acc[mi][ni][0]); o.y = f2b(acc[mi][ni][1]);
            o.z = f2b(acc[mi][ni][2]); o.w = f2b(acc[mi][ni][3]);
            *(ushort4*)(C + (size_t)m * 256 + col) = o;
        }
    }
}

// ---------------------------------------------------------------------------
// Fused z+h GRU step. z tile in LDS (R15 proved LDS beats registers here).
// SINGLE-buffered staging: As 16KB + Bs 8KB + Zs 16KB = 40KB -> 4 blocks/CU
// (R14's dbuf version was 64KB -> 2 blocks, 16.5% occupancy, 45.5us).
// Reg-prefetch retained: next step's loads issue before current mma.
__global__ __launch_bounds__(256) void k_mg_zh(
    const u16* __restrict__ sumh, const u16* __restrict__ sumgh,
    const u16* __restrict__ BzhT, const u16* __restrict__ BhhT,
    const u16* __restrict__ Pzx, const u16* __restrict__ Phx,
    const float* __restrict__ bz, const float* __restrict__ bh,
    u16* __restrict__ h) {
    __shared__ u16 As[8192], Bs[4096], Zs[8192];
    GT_PROLOG((int)blockIdx.x, (int)gridDim.x)
    uint4 ra[4], rb[2];
    // ---- phase 1: z = sigm(sumh@Bzh^T + Pzx + bz) -> Zs ----
    {
        f32x4 acc[4][2]; ACC_INIT(acc)
        ldA(sumh, m0, 256, 0, tid, ra); ldB(BzhT, n0, 256, 0, tid, rb);
        SB_STEP((ldA(sumh, m0, 256, 64, tid, ra),  ldB(BzhT, n0, 256, 64, tid, rb)))
        SB_STEP((ldA(sumh, m0, 256, 128, tid, ra), ldB(BzhT, n0, 256, 128, tid, rb)))
        SB_STEP((ldA(sumh, m0, 256, 192, tid, ra), ldB(BzhT, n0, 256, 192, tid, rb)))
        wrA(As, tid, ra); wrB(Bs, tid, rb);
        __syncthreads();
        mma_step(As, Bs, acc, lane, wr, wc);
        #pragma unroll
        for (int mi = 0; mi < 4; ++mi) {
            int m = (int)m0 + row_l + (mi << 4);
            #pragma unroll
            for (int ni = 0; ni < 2; ++ni) {
                int col = (int)n0 + col_l + (ni << 4);
                float4 vz = *(const float4*)(bz + col);
                ushort4 p4 = (m < 40000)
                    ? *(const ushort4*)(Pzx + (size_t)m * 256 + col)
                    : make_ushort4(0, 0, 0, 0);
                ushort4 o;
                o.x = f2b(sigm(acc[mi][ni][0] + b2f(p4.x) + vz.x));
                o.y = f2b(sigm(acc[mi][ni][1] + b2f(p4.y) + vz.y));
                o.z = f2b(sigm(acc[mi][ni][2] + b2f(p4.z) + vz.z));
                o.w = f2b(sigm(acc[mi][ni][3] + b2f(p4.w) + vz.w));
                int rr = row_l + (mi << 4);
                int cc = col_l + (ni << 4);
                int byte = (((rr << 6) + cc) << 1) ^ ((rr & 7) << 4);
                *(ushort4*)((char*)Zs + byte) = o;
            }
        }
    }
    __syncthreads();   // phase boundary: all mma reads + Zs writes complete
    // ---- phase 2: pre = tanh(sumgh@Bhh^T + Phx + bh); GRU combine ----
    {
        f32x4 acc[4][2]; ACC_INIT(acc)
        ldA(sumgh, m0, 256, 0, tid, ra); ldB(BhhT, n0, 256, 0, tid, rb);
        SB_STEP((ldA(sumgh, m0, 256, 64, tid, ra),  ldB(BhhT, n0, 256, 64, tid, rb)))
        SB_STEP((ldA(sumgh, m0, 256, 128, tid, ra), ldB(BhhT, n0, 256, 128, tid, rb)))
        SB_STEP((ldA(sumgh, m0, 256, 192, tid, ra), ldB(BhhT, n0, 256, 192, tid, rb)))
        wrA(As, tid, ra); wrB(Bs, tid, rb);
        __syncthreads();
        mma_step(As, Bs, acc, lane, wr, wc);
        #pragma unroll
        for (int mi = 0; mi < 4; ++mi) {
            int m = (int)m0 + row_l + (mi << 4);
            if (m >= 40000) continue;
            #pragma unroll
            for (int ni = 0; ni < 2; ++ni) {
                int col = (int)n0 + col_l + (ni << 4);
                float4 vh = *(const float4*)(bh + col);
                ushort4 p4  = *(const ushort4*)(Phx  + (size_t)m * 256 + col);
                ushort4 sh4 = *(const ushort4*)(sumh + (size_t)m * 256 + col);
                int rr = row_l + (mi << 4);
                int cc = col_l + (ni << 4);
                int byte = (((rr << 6) + cc) << 1) ^ ((rr & 7) << 4);
                ushort4 z4 = *(const ushort4*)((const char*)Zs + byte);
                float pv[4]  = {b2f(p4.x),  b2f(p4.y),  b2f(p4.z),  b2f(p4.w)};
                float zv[4]  = {b2f(z4.x),  b2f(z4.y),  b2f(z4.z),  b2f(z4.w)};
                float shv[4] = {b2f(sh4.x), b2f(sh4.y), b2f(sh4.z), b2f(sh4.w)};
                float bhv[4] = {vh.x, vh.y, vh.z, vh.w};
                float o[4];
                #pragma unroll
                for (int q = 0; q < 4; ++q) {
                    float pre = tanh_(acc[mi][ni][q] + pv[q] + bhv[q]);
                    o[q] = (1.0f - zv[q]) * shv[q] + zv[q] * pre;
                }
                if (m == 0) { o[0] = o[1] = o[2] = o[3] = 0.0f; }
                ushort4 ov;
                ov.x = f2b(o[0]); ov.y = f2b(o[1]); ov.z = f2b(o[2]); ov.w = f2b(o[3]);
                *(ushort4*)(h + (size_t)m * 256 + col) = ov;
            }
        }
    }
}

// out = gelu(nei@BohT^T + Pn + bo), in-place on d_out. K=256, M=20000. Grid 628.
__global__ __launch_bounds__(256) void k_mg_out(
    const u16* __restrict__ nei, const u16* __restrict__ BT,
    const float* __restrict__ bo, float* __restrict__ out) {
    __shared__ u16 As0[8192], As1[8192], Bs0[4096], Bs1[4096];
    GT_PROLOG((int)blockIdx.x, (int)gridDim.x)
    f32x4 acc[4][2]; ACC_INIT(acc)
    uint4 ra[4], rb[2];
    ldA(nei, m0, 256, 0, tid, ra); ldB(BT, n0, 256, 0, tid, rb);
    wrA(As0, tid, ra); wrB(Bs0, tid, rb);
    __syncthreads();
    ldA(nei, m0, 256, 64, tid, ra); ldB(BT, n0, 256, 64, tid, rb);
    DB_STEP(As0, Bs0, As1, Bs1, (ldA(nei, m0, 256, 128, tid, ra), ldB(BT, n0, 256, 128, tid, rb)))
    DB_STEP(As1, Bs1, As0, Bs0, (ldA(nei, m0, 256, 192, tid, ra), ldB(BT, n0, 256, 192, tid, rb)))
    DB_STEP(As0, Bs0, As1, Bs1, ;)
    mma_step(As1, Bs1, acc, lane, wr, wc);
    #pragma unroll
    for (int mi = 0; mi < 4; ++mi) {
        int m = (int)m0 + row_l + (mi << 4);
        if (m >= 20000) continue;
        #pragma unroll
        for (int ni = 0; ni < 2; ++ni) {
            int col = (int)n0 + col_l + (ni << 4);
            float4 vb = *(const float4*)(bo + col);
            const float bv[4] = {vb.x, vb.y, vb.z, vb.w};
            float o[4];
            #pragma unroll
            for (int q = 0; q < 4; ++q) {
                float pn = out[(size_t)m * 256 + col + q];
                o[q] = (m == 0) ? 0.0f : gelu_(acc[mi][ni][q] + pn + bv[q]);
            }
            #pragma unroll
            for (int q = 0; q < 4; ++q)
                out[(size_t)m * 256 + col + q] = o[q];
        }
    }
}

// ---------------------------------------------------------------------------
// sumh/sumgh gather (32 thr/edge, 2-stage pipelined). Grid 5000x256.
__global__ __launch_bounds__(256) void k_gather_edge(
    const u16* __restrict__ h, const u16* __restrict__ Uh,
    const u16* __restrict__ PrU, const int* __restrict__ bgraph,
    u16* __restrict__ sumh, u16* __restrict__ sumgh) {
    int e = (blockIdx.x << 3) + (threadIdx.x >> 5);
    int c = (threadIdx.x & 31) << 3;
    size_t o = (size_t)e * 256 + c;
    int bi[6];
    *(int2*)&bi[0] = *(const int2*)(bgraph + e * 6 + 0);
    *(int2*)&bi[2] = *(const int2*)(bgraph + e * 6 + 2);
    *(int2*)&bi[4] = *(const int2*)(bgraph + e * 6 + 4);
    float pr[8];
    u4tof8(*(const uint4*)(PrU + o), pr);
    float sh[8] = {}, sg[8] = {};
    uint4 hv4 = *(const uint4*)(h  + (size_t)bi[0] * 256 + c);
    uint4 uv4 = *(const uint4*)(Uh + (size_t)bi[0] * 256 + c);
    #pragma unroll
    for (int j = 0; j < 6; ++j) {
        uint4 hn, un;
        if (j < 5) {
            hn = *(const uint4*)(h  + (size_t)bi[j + 1] * 256 + c);
            un = *(const uint4*)(Uh + (size_t)bi[j + 1] * 256 + c);
        }
        float hv[8], uv[8];
        u4tof8(hv4, hv); u4tof8(uv4, uv);
        #pragma unroll
        for (int q = 0; q < 8; ++q) {
            sh[q] += hv[q];
            sg[q] += sigm(pr[q] + uv[q]) * hv[q];
        }
        hv4 = hn; uv4 = un;
    }
    *(uint4*)(sumh  + o) = f8tou4(sh);
    *(uint4*)(sumgh + o) = f8tou4(sg);
}

// nei[n] = bf16(sum_j h[agraph[n][j]]). Grid 2500x256.
__global__ __launch_bounds__(256) void k_gather_node(
    const u16* __restrict__ h, const int* __restrict__ agraph,
    u16* __restrict__ nei) {
    int n = (blockIdx.x << 3) + (threadIdx.x >> 5);
    int c = (threadIdx.x & 31) << 3;
    int ai[6];
    *(int2*)&ai[0] = *(const int2*)(agraph + n * 6 + 0);
    *(int2*)&ai[2] = *(const int2*)(agraph + n * 6 + 2);
    *(int2*)&ai[4] = *(const int2*)(agraph + n * 6 + 4);
    float s[8] = {};
    uint4 hv4 = *(const uint4*)(h + (size_t)ai[0] * 256 + c);
    #pragma unroll
    for (int j = 0; j < 6; ++j) {
        uint4 hn;
        if (j < 5) hn = *(const uint4*)(h + (size_t)ai[j + 1] * 256 + c);
        float hv[8];
        u4tof8(hv4, hv);
        #pragma unroll
        for (int q = 0; q < 8; ++q) s[q] += hv[q];
        hv4 = hn;
    }
    *(uint4*)(nei + (size_t)n * 256 + c) = f8tou4(s);
}

// ---------------------------------------------------------------------------
extern "C" void kernel_launch(void* const* d_in, const int* in_sizes, int n_in,
                              void* d_out, int out_size, void* d_ws, size_t ws_size,
                              hipStream_t stream) {
    if (ws_size < WS_BYTES) return;

    const float* fnode  = (const float*)d_in[0];
    const float* fmess  = (const float*)d_in[1];
    const int*   agraph = (const int*)d_in[2];
    const int*   bgraph = (const int*)d_in[3];
    const float* Wz  = (const float*)d_in[4];
    const float* bz  = (const float*)d_in[5];
    const float* Wr  = (const float*)d_in[6];
    const float* Ur  = (const float*)d_in[7];
    const float* urb = (const float*)d_in[8];
    const float* Wh  = (const float*)d_in[9];
    const float* bh  = (const float*)d_in[10];
    const float* Wo  = (const float*)d_in[11];
    const float* bo  = (const float*)d_in[12];

    char* base = (char*)d_ws;
    u16* PrU   = (u16*)(base + OB_PRU);
    u16* Pzx   = (u16*)(base + OB_PZX);
    u16* Phx   = (u16*)(base + OB_PHX);
    u16* h     = (u16*)(base + OB_H);
    u16* Uh    = (u16*)(base + OB_UH);
    u16* nei   = (u16*)(base + OB_UH);   // overlay: after depth loop
    u16* sumh  = (u16*)(base + OB_SH);
    u16* x     = (u16*)(base + OB_SH);   // overlay: prologue only
    u16* sumgh = (u16*)(base + OB_SGH);
    u16* fb    = (u16*)(base + OB_SGH);  // overlay: prologue only
    u16* BzxT  = (u16*)(base + OB_BZX);
    u16* BzhT  = (u16*)(base + OB_BZH);
    u16* BhxT  = (u16*)(base + OB_BHX);
    u16* BhhT  = (u16*)(base + OB_BHH);
    u16* BuT   = (u16*)(base + OB_BU);
    u16* BohT  = (u16*)(base + OB_BOH);
    u16* BrT   = (u16*)(base + OB_BR);   // prologue-only (UH overlay)
    u16* BoxT  = (u16*)(base + OB_BOX);  // prologue-only (UH overlay)
    float* out = (float*)d_out;

    hipLaunchKernelGGL(k_repack, dim3(256), dim3(256), 0, stream,
                       Wz, Wr, Ur, Wh, Wo, BzxT, BzhT, BhxT, BhhT, BuT, BohT, BrT, BoxT);
    hipLaunchKernelGGL(k_build_x, dim3(20000), dim3(256), 0, stream, fnode, fmess, x);
    hipLaunchKernelGGL(k_build_fb, dim3(10000), dim3(256), 0, stream, fnode, fb);
    hipLaunchKernelGGL(k_mg_pre, dim3(3756), dim3(256), 0, stream,
                       x, BrT, BzxT, BhxT, urb, PrU, Pzx, Phx);
    hipLaunchKernelGGL(k_mg_pn, dim3(628), dim3(256), 0, stream, fb, BoxT, out);
    hipLaunchKernelGGL(k_d1, dim3(5000), dim3(256), 0, stream, Pzx, Phx, bz, bh, h);
    for (int d = 1; d < 4; ++d) {
        hipLaunchKernelGGL(k_mg_uh, dim3(1252), dim3(256), 0, stream, h, BuT, Uh);
        hipLaunchKernelGGL(k_gather_edge, dim3(5000), dim3(256), 0, stream,
                           h, Uh, PrU, bgraph, sumh, sumgh);
        hipLaunchKernelGGL(k_mg_zh, dim3(1252), dim3(256), 0, stream,
                           sumh, sumgh, BzhT, BhhT, Pzx, Phx, bz, bh, h);
    }
    hipLaunchKernelGGL(k_gather_node, dim3(2500), dim3(256), 0, stream, h, agraph, nei);
    hipLaunchKernelGGL(k_mg_out, dim3(628), dim3(256), 0, stream, nei, BohT, bo, out);
}

// Round 17
// 426.319 us; speedup vs baseline: 1.2732x; 1.2732x over previous
//
#include <hip/hip_runtime.h>
#include <cstddef>
#include <cstdint>

typedef unsigned short u16;
typedef unsigned int   u32;
typedef __bf16  bf16x8 __attribute__((ext_vector_type(8)));
typedef float   f32x4  __attribute__((ext_vector_type(4)));

#define DEV __device__ __forceinline__

DEV float b2f(u16 u) { union { u32 i; float f; } c; c.i = ((u32)u) << 16; return c.f; }
DEV u16 f2b(float x) { union { float f; u32 i; } c; c.f = x; u32 b = c.i;
                       return (u16)((b + 0x7FFFu + ((b >> 16) & 1u)) >> 16); }
DEV float sigm(float x)  { return 1.0f / (1.0f + __expf(-x)); }
DEV float tanh_(float x) { return 1.0f - 2.0f / (1.0f + __expf(2.0f * x)); }
DEV float gelu_(float x) { return 0.5f * x * (1.0f + erff(x * 0.70710678118654752f)); }

DEV void u4tof8(uint4 v, float* f) {
    f[0] = b2f((u16)(v.x & 0xFFFF)); f[1] = b2f((u16)(v.x >> 16));
    f[2] = b2f((u16)(v.y & 0xFFFF)); f[3] = b2f((u16)(v.y >> 16));
    f[4] = b2f((u16)(v.z & 0xFFFF)); f[5] = b2f((u16)(v.z >> 16));
    f[6] = b2f((u16)(v.w & 0xFFFF)); f[7] = b2f((u16)(v.w >> 16));
}
DEV uint4 f8tou4(const float* f) {
    uint4 v;
    v.x = (u32)f2b(f[0]) | ((u32)f2b(f[1]) << 16);
    v.y = (u32)f2b(f[2]) | ((u32)f2b(f[3]) << 16);
    v.z = (u32)f2b(f[4]) | ((u32)f2b(f[5]) << 16);
    v.w = (u32)f2b(f[6]) | ((u32)f2b(f[7]) << 16);
    return v;
}

// ---- workspace byte offsets; total 144,015,360 B (<=144,113,664 proven) ----
#define OB_PRU   0ull            // PrU [40000][256] bf16 (x@Wr^T + urb)
#define OB_PZX   20480000ull     // Pzx [40000][256] bf16 (x@Wzx^T, depth-invariant)
#define OB_PHX   40960000ull     // Phx [40000][256] bf16
#define OB_H     61440000ull     // h   [40000][256] bf16
#define OB_UH    81920000ull     // Uh [40000][256] bf16; nei overlay; Br/Box overlay in prologue
#define OB_SH    102400000ull    // sumh [40000][256] bf16 ; x overlays in prologue
#define OB_SGH   122880000ull    // sumgh [40000][256] bf16 ; fb overlays in prologue
#define OB_BZX   143360000ull    // [256][128] Wz[:, :111] K-pad
#define OB_BZH   143425536ull    // [256][256] Wz[:, 111:]
#define OB_BHX   143556608ull    // [256][128] Wh[:, :111]
#define OB_BHH   143622144ull    // [256][256] Wh[:, 111:]
#define OB_BU    143753216ull    // [256][256] U_r
#define OB_BOH   143884288ull    // [256][256] Wo[:, 98:]
#define OB_BR    OB_UH           // [256][128] Wr (prologue only; clobbered by Uh)
#define OB_BOX   (OB_UH + 65536ull) // [256][128] Wo[:, :98] (prologue only)
#define WS_BYTES 144015360ull

// REGISTER/LDS LAW (R3-R16): the allocator's VGPR cap is a non-monotonic
// function of LDS size: 64KB->cap>=88 ok, 48KB->cap>=92 ok, 40KB->cap 68
// SPILLS, 24KB->cap~85. k_mg_zh needs ~85 live: keep it at 64KB (R14 form).
// Z-TILE LAW (R15): LDS hand-off beats registers (45.5 vs 57us).
// R14 = 427us measured; this file restores it exactly.

// XCD-aware bijective swizzle (T1/m204).
DEV int xcd_swz(int bid, int nwg) {
    int q = nwg >> 3, r = nwg & 7;
    int xcd = bid & 7, idx = bid >> 3;
    return (xcd < r ? xcd * (q + 1) : r * (q + 1) + (xcd - r) * q) + idx;
}

// ---------------------------------------------------------------------------
// Weight repack -> [N][K] bf16. Grid 256x256.
__global__ __launch_bounds__(256) void k_repack(
    const float* __restrict__ Wz, const float* __restrict__ Wr,
    const float* __restrict__ Ur, const float* __restrict__ Wh,
    const float* __restrict__ Wo,
    u16* __restrict__ BzxT, u16* __restrict__ BzhT, u16* __restrict__ BhxT,
    u16* __restrict__ BhhT, u16* __restrict__ BuT, u16* __restrict__ BohT,
    u16* __restrict__ BrT, u16* __restrict__ BoxT) {
    int idx = blockIdx.x * 256 + threadIdx.x;   // 0..65535
    {
        int n = idx >> 8, k = idx & 255;
        BzhT[idx] = f2b(Wz[n * 367 + 111 + k]);
        BhhT[idx] = f2b(Wh[n * 367 + 111 + k]);
        BuT[idx]  = f2b(Ur[idx]);
        BohT[idx] = f2b(Wo[n * 354 + 98 + k]);
    }
    if (idx < 32768) {
        int n = idx >> 7, k = idx & 127;
        BzxT[idx] = f2b(k < 111 ? Wz[n * 367 + k] : 0.0f);
        BhxT[idx] = f2b(k < 111 ? Wh[n * 367 + k] : 0.0f);
        BrT[idx]  = f2b(k < 111 ? Wr[n * 111 + k] : 0.0f);
        BoxT[idx] = f2b(k < 98  ? Wo[n * 354 + k] : 0.0f);
    }
}

// x[e][c] (bf16, [40000][128], zero pad). Grid 20000x256.
__global__ __launch_bounds__(256) void k_build_x(const float* __restrict__ fnode,
                                                 const float* __restrict__ fmess,
                                                 u16* __restrict__ x) {
    int e = (blockIdx.x << 1) + (threadIdx.x >> 7);
    int c = threadIdx.x & 127;
    int src = (int)fmess[(size_t)e * 15];
    float v = 0.0f;
    if (c < 98)       v = fnode[(size_t)src * 98 + c];
    else if (c < 111) v = fmess[(size_t)e * 15 + 2 + (c - 98)];
    x[(size_t)e * 128 + c] = f2b(v);
}

// fb [20000][128] bf16 zero-padded. Grid 10000x256.
__global__ __launch_bounds__(256) void k_build_fb(const float* __restrict__ fnode,
                                                  u16* __restrict__ fb) {
    int idx = blockIdx.x * 256 + threadIdx.x;
    int n = idx >> 7, c = idx & 127;
    fb[idx] = f2b(c < 98 ? fnode[(size_t)n * 98 + c] : 0.0f);
}

// ---------------------------------------------------------------------------
// R11 template: BM=128, BN=64, BK=64. 256 threads = 4 waves (2M x 2N),
// wave tile 64x32, acc[4][2]. LDS 48KB dbuf, swizzle byte ^= (row&7)<<4.
DEV void ldA(const u16* __restrict__ g, size_t row0, int ld, int k0, int tid, uint4* v) {
    #pragma unroll
    for (int it = 0; it < 4; ++it) {
        int r = it * 32 + (tid >> 3);
        int c = (tid & 7) << 3;
        v[it] = *(const uint4*)(g + (row0 + (size_t)r) * ld + k0 + c);
    }
}
DEV void ldB(const u16* __restrict__ g, size_t row0, int ld, int k0, int tid, uint4* v) {
    #pragma unroll
    for (int it = 0; it < 2; ++it) {
        int r = it * 32 + (tid >> 3);
        int c = (tid & 7) << 3;
        v[it] = *(const uint4*)(g + (row0 + (size_t)r) * ld + k0 + c);
    }
}
DEV void wrA(u16* s, int tid, const uint4* v) {
    #pragma unroll
    for (int it = 0; it < 4; ++it) {
        int r = it * 32 + (tid >> 3);
        int c = (tid & 7) << 3;
        int byte = (((r << 6) + c) << 1) ^ ((r & 7) << 4);
        *(uint4*)((char*)s + byte) = v[it];
    }
}
DEV void wrB(u16* s, int tid, const uint4* v) {
    #pragma unroll
    for (int it = 0; it < 2; ++it) {
        int r = it * 32 + (tid >> 3);
        int c = (tid & 7) << 3;
        int byte = (((r << 6) + c) << 1) ^ ((r & 7) << 4);
        *(uint4*)((char*)s + byte) = v[it];
    }
}
// Swapped-operand MFMA: acc[i][j][q] = C[row_l+16i][col_l+16j+q]
DEV void mma_step(const u16* As, const u16* Bs, f32x4 acc[4][2], int lane, int wr, int wc) {
    int rb = (wr << 6) + (lane & 15);
    int cb = (wc << 5) + (lane & 15);
    int ko = (lane >> 4) << 3;
    #pragma unroll
    for (int kh = 0; kh < 2; ++kh) {
        bf16x8 a[4], b[2];
        #pragma unroll
        for (int i = 0; i < 4; ++i) {
            int ar = rb + (i << 4);
            a[i] = *(const bf16x8*)((const char*)As +
                   ((((ar << 6) + (kh << 5) + ko) << 1) ^ ((ar & 7) << 4)));
        }
        #pragma unroll
        for (int j = 0; j < 2; ++j) {
            int br = cb + (j << 4);
            b[j] = *(const bf16x8*)((const char*)Bs +
                   ((((br << 6) + (kh << 5) + ko) << 1) ^ ((br & 7) << 4)));
        }
        #pragma unroll
        for (int i = 0; i < 4; ++i)
            #pragma unroll
            for (int j = 0; j < 2; ++j)
                acc[i][j] = __builtin_amdgcn_mfma_f32_16x16x32_bf16(b[j], a[i], acc[i][j], 0, 0, 0);
    }
}

#define GT_PROLOG(BIDX, NWG)                                   \
    int tid = threadIdx.x, lane = tid & 63, w = tid >> 6;      \
    int wr = w >> 1, wc = w & 1;                               \
    int bid = xcd_swz((BIDX), (NWG));                          \
    int bm = bid >> 2, bn = bid & 3;                           \
    size_t m0 = (size_t)bm << 7; size_t n0 = (size_t)(bn << 6);\
    int row_l = (wr << 6) + (lane & 15);                       \
    int col_l = (wc << 5) + ((lane >> 4) << 2);

#define ACC_INIT(A)                                            \
    { f32x4 zz = {0.f, 0.f, 0.f, 0.f};                         \
      _Pragma("unroll") for (int i = 0; i < 4; ++i)            \
      _Pragma("unroll") for (int j = 0; j < 2; ++j) A[i][j] = zz; }

#define DB_STEP(CUR_A, CUR_B, NXT_A, NXT_B, LD_NEXT2)          \
    mma_step(CUR_A, CUR_B, acc, lane, wr, wc);                 \
    wrA(NXT_A, tid, ra); wrB(NXT_B, tid, rb);                  \
    __syncthreads();                                           \
    LD_NEXT2;

// ---------------------------------------------------------------------------
// Merged prologue GEMMs (K=128): sub 0: PrU = x@BrT^T + urb; sub 1: Pzx;
// sub 2: Phx. Grid 3756 (3 x 1252).
__global__ __launch_bounds__(256) void k_mg_pre(
    const u16* __restrict__ x, const u16* __restrict__ BrT,
    const u16* __restrict__ BzxT, const u16* __restrict__ BhxT,
    const float* __restrict__ urb,
    u16* __restrict__ PrU, u16* __restrict__ Pzx, u16* __restrict__ Phx) {
    __shared__ u16 As0[8192], As1[8192], Bs0[4096], Bs1[4096];
    int sub = blockIdx.x / 1252;
    int inner = blockIdx.x - sub * 1252;
    const u16* BT = sub == 0 ? BrT : (sub == 1 ? BzxT : BhxT);
    const float* bias = sub == 0 ? urb : (const float*)0;
    u16* out = sub == 0 ? PrU : (sub == 1 ? Pzx : Phx);
    GT_PROLOG(inner, 1252)
    f32x4 acc[4][2]; ACC_INIT(acc)
    uint4 ra[4], rb[2];
    ldA(x, m0, 128, 0, tid, ra); ldB(BT, n0, 128, 0, tid, rb);
    wrA(As0, tid, ra); wrB(Bs0, tid, rb);
    __syncthreads();
    ldA(x, m0, 128, 64, tid, ra); ldB(BT, n0, 128, 64, tid, rb);
    DB_STEP(As0, Bs0, As1, Bs1, ;)
    mma_step(As1, Bs1, acc, lane, wr, wc);
    #pragma unroll
    for (int mi = 0; mi < 4; ++mi) {
        int m = (int)m0 + row_l + (mi << 4);
        if (m >= 40000) continue;
        #pragma unroll
        for (int ni = 0; ni < 2; ++ni) {
            int col = (int)n0 + col_l + (ni << 4);
            float4 ub = bias ? *(const float4*)(bias + col)
                             : make_float4(0.f, 0.f, 0.f, 0.f);
            ushort4 o;
            o.x = f2b(acc[mi][ni][0] + ub.x); o.y = f2b(acc[mi][ni][1] + ub.y);
            o.z = f2b(acc[mi][ni][2] + ub.z); o.w = f2b(acc[mi][ni][3] + ub.w);
            *(ushort4*)(out + (size_t)m * 256 + col) = o;
        }
    }
}

// Pn = fb @ BoxT^T -> f32 d_out. K=128, M=20000. Grid 628.
__global__ __launch_bounds__(256) void k_mg_pn(
    const u16* __restrict__ fb, const u16* __restrict__ BT,
    float* __restrict__ out) {
    __shared__ u16 As0[8192], As1[8192], Bs0[4096], Bs1[4096];
    GT_PROLOG((int)blockIdx.x, (int)gridDim.x)
    f32x4 acc[4][2]; ACC_INIT(acc)
    uint4 ra[4], rb[2];
    ldA(fb, m0, 128, 0, tid, ra); ldB(BT, n0, 128, 0, tid, rb);
    wrA(As0, tid, ra); wrB(Bs0, tid, rb);
    __syncthreads();
    ldA(fb, m0, 128, 64, tid, ra); ldB(BT, n0, 128, 64, tid, rb);
    DB_STEP(As0, Bs0, As1, Bs1, ;)
    mma_step(As1, Bs1, acc, lane, wr, wc);
    #pragma unroll
    for (int mi = 0; mi < 4; ++mi) {
        int m = (int)m0 + row_l + (mi << 4);
        if (m >= 20000) continue;
        #pragma unroll
        for (int ni = 0; ni < 2; ++ni) {
            int col = (int)n0 + col_l + (ni << 4);
            #pragma unroll
            for (int q = 0; q < 4; ++q)
                out[(size_t)m * 256 + col + q] = acc[mi][ni][q];
        }
    }
}

// Depth-1 elementwise: h = sigm(Pzx+bz)*tanh(Phx+bh), row0 mask. Grid 5000.
__global__ __launch_bounds__(256) void k_d1(
    const u16* __restrict__ Pzx, const u16* __restrict__ Phx,
    const float* __restrict__ bz, const float* __restrict__ bh,
    u16* __restrict__ h) {
    int idx = blockIdx.x * 256 + threadIdx.x;
    int e = idx >> 5, c = (idx & 31) << 3;
    size_t o = (size_t)e * 256 + c;
    float pz[8], ph[8], r[8];
    u4tof8(*(const uint4*)(Pzx + o), pz);
    u4tof8(*(const uint4*)(Phx + o), ph);
    #pragma unroll
    for (int q = 0; q < 8; ++q)
        r[q] = (e == 0) ? 0.0f : sigm(pz[q] + bz[c + q]) * tanh_(ph[q] + bh[c + q]);
    *(uint4*)(h + o) = f8tou4(r);
}

// Uh = h @ BuT^T. K=256, 4 dbuf steps. Grid 1252.
__global__ __launch_bounds__(256) void k_mg_uh(
    const u16* __restrict__ A, const u16* __restrict__ BT, u16* __restrict__ C) {
    __shared__ u16 As0[8192], As1[8192], Bs0[4096], Bs1[4096];
    GT_PROLOG((int)blockIdx.x, (int)gridDim.x)
    f32x4 acc[4][2]; ACC_INIT(acc)
    uint4 ra[4], rb[2];
    ldA(A, m0, 256, 0, tid, ra); ldB(BT, n0, 256, 0, tid, rb);
    wrA(As0, tid, ra); wrB(Bs0, tid, rb);
    __syncthreads();
    ldA(A, m0, 256, 64, tid, ra); ldB(BT, n0, 256, 64, tid, rb);
    DB_STEP(As0, Bs0, As1, Bs1, (ldA(A, m0, 256, 128, tid, ra), ldB(BT, n0, 256, 128, tid, rb)))
    DB_STEP(As1, Bs1, As0, Bs0, (ldA(A, m0, 256, 192, tid, ra), ldB(BT, n0, 256, 192, tid, rb)))
    DB_STEP(As0, Bs0, As1, Bs1, ;)
    mma_step(As1, Bs1, acc, lane, wr, wc);
    #pragma unroll
    for (int mi = 0; mi < 4; ++mi) {
        int m = (int)m0 + row_l + (mi << 4);
        if (m >= 40000) continue;
        #pragma unroll
        for (int ni = 0; ni < 2; ++ni) {
            int col = (int)n0 + col_l + (ni << 4);
            ushort4 o;
            o.x = f2b(acc[mi][ni][0]); o.y = f2b(acc[mi][ni][1]);
            o.z = f2b(acc[mi][ni][2]); o.w = f2b(acc[mi][ni][3]);
            *(ushort4*)(C + (size_t)m * 256 + col) = o;
        }
    }
}

// ---------------------------------------------------------------------------
// Fused z+h GRU step (R14 form, 427us total measured). Two sequential
// single-acc GEMMs; z tile kept in LDS. 64KB LDS, dbuf staging.
__global__ __launch_bounds__(256) void k_mg_zh(
    const u16* __restrict__ sumh, const u16* __restrict__ sumgh,
    const u16* __restrict__ BzhT, const u16* __restrict__ BhhT,
    const u16* __restrict__ Pzx, const u16* __restrict__ Phx,
    const float* __restrict__ bz, const float* __restrict__ bh,
    u16* __restrict__ h) {
    __shared__ u16 As0[8192], As1[8192], Bs0[4096], Bs1[4096];
    __shared__ u16 Zs[8192];   // 128x64 bf16 z-tile
    GT_PROLOG((int)blockIdx.x, (int)gridDim.x)
    uint4 ra[4], rb[2];
    // ---- phase 1: z-GEMM ----
    {
        f32x4 acc[4][2]; ACC_INIT(acc)
        ldA(sumh, m0, 256, 0, tid, ra); ldB(BzhT, n0, 256, 0, tid, rb);
        wrA(As0, tid, ra); wrB(Bs0, tid, rb);
        __syncthreads();
        ldA(sumh, m0, 256, 64, tid, ra); ldB(BzhT, n0, 256, 64, tid, rb);
        DB_STEP(As0, Bs0, As1, Bs1, (ldA(sumh, m0, 256, 128, tid, ra), ldB(BzhT, n0, 256, 128, tid, rb)))
        DB_STEP(As1, Bs1, As0, Bs0, (ldA(sumh, m0, 256, 192, tid, ra), ldB(BzhT, n0, 256, 192, tid, rb)))
        DB_STEP(As0, Bs0, As1, Bs1, ;)
        mma_step(As1, Bs1, acc, lane, wr, wc);
        #pragma unroll
        for (int mi = 0; mi < 4; ++mi) {
            int m = (int)m0 + row_l + (mi << 4);
            if (m >= 40000) continue;
            #pragma unroll
            for (int ni = 0; ni < 2; ++ni) {
                int col = (int)n0 + col_l + (ni << 4);
                float4 vz = *(const float4*)(bz + col);
                ushort4 p4 = *(const ushort4*)(Pzx + (size_t)m * 256 + col);
                ushort4 o;
                o.x = f2b(sigm(acc[mi][ni][0] + b2f(p4.x) + vz.x));
                o.y = f2b(sigm(acc[mi][ni][1] + b2f(p4.y) + vz.y));
                o.z = f2b(sigm(acc[mi][ni][2] + b2f(p4.z) + vz.z));
                o.w = f2b(sigm(acc[mi][ni][3] + b2f(p4.w) + vz.w));
                int rr = row_l + (mi << 4);
                int cc = col_l + (ni << 4);
                int byte = (((rr << 6) + cc) << 1) ^ ((rr & 7) << 4);
                *(ushort4*)((char*)Zs + byte) = o;
            }
        }
    }
    __syncthreads();   // phase boundary: Zs writes + last mma reads complete
    // ---- phase 2: h-GEMM ----
    {
        f32x4 acc[4][2]; ACC_INIT(acc)
        ldA(sumgh, m0, 256, 0, tid, ra); ldB(BhhT, n0, 256, 0, tid, rb);
        wrA(As0, tid, ra); wrB(Bs0, tid, rb);
        __syncthreads();
        ldA(sumgh, m0, 256, 64, tid, ra); ldB(BhhT, n0, 256, 64, tid, rb);
        DB_STEP(As0, Bs0, As1, Bs1, (ldA(sumgh, m0, 256, 128, tid, ra), ldB(BhhT, n0, 256, 128, tid, rb)))
        DB_STEP(As1, Bs1, As0, Bs0, (ldA(sumgh, m0, 256, 192, tid, ra), ldB(BhhT, n0, 256, 192, tid, rb)))
        DB_STEP(As0, Bs0, As1, Bs1, ;)
        mma_step(As1, Bs1, acc, lane, wr, wc);
        #pragma unroll
        for (int mi = 0; mi < 4; ++mi) {
            int m = (int)m0 + row_l + (mi << 4);
            if (m >= 40000) continue;
            #pragma unroll
            for (int ni = 0; ni < 2; ++ni) {
                int col = (int)n0 + col_l + (ni << 4);
                float4 vh = *(const float4*)(bh + col);
                ushort4 p4  = *(const ushort4*)(Phx  + (size_t)m * 256 + col);
                ushort4 sh4 = *(const ushort4*)(sumh + (size_t)m * 256 + col);
                int rr = row_l + (mi << 4);
                int cc = col_l + (ni << 4);
                int byte = (((rr << 6) + cc) << 1) ^ ((rr & 7) << 4);
                ushort4 z4 = *(const ushort4*)((const char*)Zs + byte);
                float pv[4]  = {b2f(p4.x),  b2f(p4.y),  b2f(p4.z),  b2f(p4.w)};
                float zv[4]  = {b2f(z4.x),  b2f(z4.y),  b2f(z4.z),  b2f(z4.w)};
                float shv[4] = {b2f(sh4.x), b2f(sh4.y), b2f(sh4.z), b2f(sh4.w)};
                float bhv[4] = {vh.x, vh.y, vh.z, vh.w};
                float o[4];
                #pragma unroll
                for (int q = 0; q < 4; ++q) {
                    float pre = tanh_(acc[mi][ni][q] + pv[q] + bhv[q]);
                    o[q] = (1.0f - zv[q]) * shv[q] + zv[q] * pre;
                }
                if (m == 0) { o[0] = o[1] = o[2] = o[3] = 0.0f; }
                ushort4 ov;
                ov.x = f2b(o[0]); ov.y = f2b(o[1]); ov.z = f2b(o[2]); ov.w = f2b(o[3]);
                *(ushort4*)(h + (size_t)m * 256 + col) = ov;
            }
        }
    }
}

// out = gelu(nei@BohT^T + Pn + bo), in-place on d_out. K=256, M=20000. Grid 628.
__global__ __launch_bounds__(256) void k_mg_out(
    const u16* __restrict__ nei, const u16* __restrict__ BT,
    const float* __restrict__ bo, float* __restrict__ out) {
    __shared__ u16 As0[8192], As1[8192], Bs0[4096], Bs1[4096];
    GT_PROLOG((int)blockIdx.x, (int)gridDim.x)
    f32x4 acc[4][2]; ACC_INIT(acc)
    uint4 ra[4], rb[2];
    ldA(nei, m0, 256, 0, tid, ra); ldB(BT, n0, 256, 0, tid, rb);
    wrA(As0, tid, ra); wrB(Bs0, tid, rb);
    __syncthreads();
    ldA(nei, m0, 256, 64, tid, ra); ldB(BT, n0, 256, 64, tid, rb);
    DB_STEP(As0, Bs0, As1, Bs1, (ldA(nei, m0, 256, 128, tid, ra), ldB(BT, n0, 256, 128, tid, rb)))
    DB_STEP(As1, Bs1, As0, Bs0, (ldA(nei, m0, 256, 192, tid, ra), ldB(BT, n0, 256, 192, tid, rb)))
    DB_STEP(As0, Bs0, As1, Bs1, ;)
    mma_step(As1, Bs1, acc, lane, wr, wc);
    #pragma unroll
    for (int mi = 0; mi < 4; ++mi) {
        int m = (int)m0 + row_l + (mi << 4);
        if (m >= 20000) continue;
        #pragma unroll
        for (int ni = 0; ni < 2; ++ni) {
            int col = (int)n0 + col_l + (ni << 4);
            float4 vb = *(const float4*)(bo + col);
            const float bv[4] = {vb.x, vb.y, vb.z, vb.w};
            float o[4];
            #pragma unroll
            for (int q = 0; q < 4; ++q) {
                float pn = out[(size_t)m * 256 + col + q];
                o[q] = (m == 0) ? 0.0f : gelu_(acc[mi][ni][q] + pn + bv[q]);
            }
            #pragma unroll
            for (int q = 0; q < 4; ++q)
                out[(size_t)m * 256 + col + q] = o[q];
        }
    }
}

// ---------------------------------------------------------------------------
// sumh/sumgh gather (32 thr/edge, 2-stage pipelined). Grid 5000x256.
__global__ __launch_bounds__(256) void k_gather_edge(
    const u16* __restrict__ h, const u16* __restrict__ Uh,
    const u16* __restrict__ PrU, const int* __restrict__ bgraph,
    u16* __restrict__ sumh, u16* __restrict__ sumgh) {
    int e = (blockIdx.x << 3) + (threadIdx.x >> 5);
    int c = (threadIdx.x & 31) << 3;
    size_t o = (size_t)e * 256 + c;
    int bi[6];
    *(int2*)&bi[0] = *(const int2*)(bgraph + e * 6 + 0);
    *(int2*)&bi[2] = *(const int2*)(bgraph + e * 6 + 2);
    *(int2*)&bi[4] = *(const int2*)(bgraph + e * 6 + 4);
    float pr[8];
    u4tof8(*(const uint4*)(PrU + o), pr);
    float sh[8] = {}, sg[8] = {};
    uint4 hv4 = *(const uint4*)(h  + (size_t)bi[0] * 256 + c);
    uint4 uv4 = *(const uint4*)(Uh + (size_t)bi[0] * 256 + c);
    #pragma unroll
    for (int j = 0; j < 6; ++j) {
        uint4 hn, un;
        if (j < 5) {
            hn = *(const uint4*)(h  + (size_t)bi[j + 1] * 256 + c);
            un = *(const uint4*)(Uh + (size_t)bi[j + 1] * 256 + c);
        }
        float hv[8], uv[8];
        u4tof8(hv4, hv); u4tof8(uv4, uv);
        #pragma unroll
        for (int q = 0; q < 8; ++q) {
            sh[q] += hv[q];
            sg[q] += sigm(pr[q] + uv[q]) * hv[q];
        }
        hv4 = hn; uv4 = un;
    }
    *(uint4*)(sumh  + o) = f8tou4(sh);
    *(uint4*)(sumgh + o) = f8tou4(sg);
}

// nei[n] = bf16(sum_j h[agraph[n][j]]). Grid 2500x256.
__global__ __launch_bounds__(256) void k_gather_node(
    const u16* __restrict__ h, const int* __restrict__ agraph,
    u16* __restrict__ nei) {
    int n = (blockIdx.x << 3) + (threadIdx.x >> 5);
    int c = (threadIdx.x & 31) << 3;
    int ai[6];
    *(int2*)&ai[0] = *(const int2*)(agraph + n * 6 + 0);
    *(int2*)&ai[2] = *(const int2*)(agraph + n * 6 + 2);
    *(int2*)&ai[4] = *(const int2*)(agraph + n * 6 + 4);
    float s[8] = {};
    uint4 hv4 = *(const uint4*)(h + (size_t)ai[0] * 256 + c);
    #pragma unroll
    for (int j = 0; j < 6; ++j) {
        uint4 hn;
        if (j < 5) hn = *(const uint4*)(h + (size_t)ai[j + 1] * 256 + c);
        float hv[8];
        u4tof8(hv4, hv);
        #pragma unroll
        for (int q = 0; q < 8; ++q) s[q] += hv[q];
        hv4 = hn;
    }
    *(uint4*)(nei + (size_t)n * 256 + c) = f8tou4(s);
}

// ---------------------------------------------------------------------------
extern "C" void kernel_launch(void* const* d_in, const int* in_sizes, int n_in,
                              void* d_out, int out_size, void* d_ws, size_t ws_size,
                              hipStream_t stream) {
    if (ws_size < WS_BYTES) return;

    const float* fnode  = (const float*)d_in[0];
    const float* fmess  = (const float*)d_in[1];
    const int*   agraph = (const int*)d_in[2];
    const int*   bgraph = (const int*)d_in[3];
    const float* Wz  = (const float*)d_in[4];
    const float* bz  = (const float*)d_in[5];
    const float* Wr  = (const float*)d_in[6];
    const float* Ur  = (const float*)d_in[7];
    const float* urb = (const float*)d_in[8];
    const float* Wh  = (const float*)d_in[9];
    const float* bh  = (const float*)d_in[10];
    const float* Wo  = (const float*)d_in[11];
    const float* bo  = (const float*)d_in[12];

    char* base = (char*)d_ws;
    u16* PrU   = (u16*)(base + OB_PRU);
    u16* Pzx   = (u16*)(base + OB_PZX);
    u16* Phx   = (u16*)(base + OB_PHX);
    u16* h     = (u16*)(base + OB_H);
    u16* Uh    = (u16*)(base + OB_UH);
    u16* nei   = (u16*)(base + OB_UH);   // overlay: after depth loop
    u16* sumh  = (u16*)(base + OB_SH);
    u16* x     = (u16*)(base + OB_SH);   // overlay: prologue only
    u16* sumgh = (u16*)(base + OB_SGH);
    u16* fb    = (u16*)(base + OB_SGH);  // overlay: prologue only
    u16* BzxT  = (u16*)(base + OB_BZX);
    u16* BzhT  = (u16*)(base + OB_BZH);
    u16* BhxT  = (u16*)(base + OB_BHX);
    u16* BhhT  = (u16*)(base + OB_BHH);
    u16* BuT   = (u16*)(base + OB_BU);
    u16* BohT  = (u16*)(base + OB_BOH);
    u16* BrT   = (u16*)(base + OB_BR);   // prologue-only (UH overlay)
    u16* BoxT  = (u16*)(base + OB_BOX);  // prologue-only (UH overlay)
    float* out = (float*)d_out;

    hipLaunchKernelGGL(k_repack, dim3(256), dim3(256), 0, stream,
                       Wz, Wr, Ur, Wh, Wo, BzxT, BzhT, BhxT, BhhT, BuT, BohT, BrT, BoxT);
    hipLaunchKernelGGL(k_build_x, dim3(20000), dim3(256), 0, stream, fnode, fmess, x);
    hipLaunchKernelGGL(k_build_fb, dim3(10000), dim3(256), 0, stream, fnode, fb);
    hipLaunchKernelGGL(k_mg_pre, dim3(3756), dim3(256), 0, stream,
                       x, BrT, BzxT, BhxT, urb, PrU, Pzx, Phx);
    hipLaunchKernelGGL(k_mg_pn, dim3(628), dim3(256), 0, stream, fb, BoxT, out);
    hipLaunchKernelGGL(k_d1, dim3(5000), dim3(256), 0, stream, Pzx, Phx, bz, bh, h);
    for (int d = 1; d < 4; ++d) {
        hipLaunchKernelGGL(k_mg_uh, dim3(1252), dim3(256), 0, stream, h, BuT, Uh);
        hipLaunchKernelGGL(k_gather_edge, dim3(5000), dim3(256), 0, stream,
                           h, Uh, PrU, bgraph, sumh, sumgh);
        hipLaunchKernelGGL(k_mg_zh, dim3(1252), dim3(256), 0, stream,
                           sumh, sumgh, BzhT, BhhT, Pzx, Phx, bz, bh, h);
    }
    hipLaunchKernelGGL(k_gather_node, dim3(2500), dim3(256), 0, stream, h, agraph, nei);
    hipLaunchKernelGGL(k_mg_out, dim3(628), dim3(256), 0, stream, nei, BohT, bo, out);
}